// Round 1
// baseline (371.725 us; speedup 1.0000x reference)
//
#include <hip/hip_runtime.h>
#include <hip/hip_bf16.h>
#include <stdint.h>

// Problem constants
#define M_DIM 8192      // 2*4096 flattened batch
#define K_DIM 2048      // ACTIVE (in)
#define N_DIM 2048      // ACTIVE (out)
#define IN_DIM 4096     // ORIG_IN
#define OUT_DIM 4096    // ORIG_OUT
#define SCALING 2.0f    // 32/16

typedef __attribute__((ext_vector_type(8))) short bf16x8_t;  // 8 bf16 = 4 VGPRs
typedef __attribute__((ext_vector_type(4))) float f32x4_t;

__device__ __forceinline__ void load_lds16(const void* gptr, void* lptr) {
    __builtin_amdgcn_global_load_lds(
        (const __attribute__((address_space(1))) uint32_t*)(uintptr_t)gptr,
        (__attribute__((address_space(3))) uint32_t*)(uintptr_t)lptr,
        16, 0, 0);
}

// ---------------------------------------------------------------------------
// Kernel 1: fold LoRA into base weight, cast to bf16.
// W_eff[o][k] = bf16( W_base[o][k] + SCALING * sum_r lora_B[o][r]*lora_A[r][k] )
// grid (2048/256, 2048), block 256
// ---------------------------------------------------------------------------
__global__ void fold_w_kernel(const float* __restrict__ Wb,
                              const float* __restrict__ lA,   // [16][2048]
                              const float* __restrict__ lB,   // [2048][16]
                              __hip_bfloat16* __restrict__ We) {
    const int k = blockIdx.x * 256 + threadIdx.x;
    const int o = blockIdx.y;
    float acc = Wb[(size_t)o * K_DIM + k];
    #pragma unroll
    for (int r = 0; r < 16; ++r)
        acc += SCALING * lB[o * 16 + r] * lA[r * K_DIM + k];
    We[(size_t)o * K_DIM + k] = __float2bfloat16(acc);
}

// ---------------------------------------------------------------------------
// Kernel 2: gather active input columns + cast to bf16.
// xs[n][k] = bf16( x[n][in_idx[k]] ).  One row per block; 8 elems/thread.
// ---------------------------------------------------------------------------
__global__ void gather_cast_kernel(const float* __restrict__ x,
                                   const int* __restrict__ idx,
                                   __hip_bfloat16* __restrict__ xs) {
    const int n = blockIdx.x;
    const int c0 = threadIdx.x * 8;
    const float* xrow = x + (size_t)n * IN_DIM;
    int4 i0 = *(const int4*)(idx + c0);
    int4 i1 = *(const int4*)(idx + c0 + 4);
    union { bf16x8_t v; __hip_bfloat16 h[8]; } u;
    u.h[0] = __float2bfloat16(xrow[i0.x]);
    u.h[1] = __float2bfloat16(xrow[i0.y]);
    u.h[2] = __float2bfloat16(xrow[i0.z]);
    u.h[3] = __float2bfloat16(xrow[i0.w]);
    u.h[4] = __float2bfloat16(xrow[i1.x]);
    u.h[5] = __float2bfloat16(xrow[i1.y]);
    u.h[6] = __float2bfloat16(xrow[i1.z]);
    u.h[7] = __float2bfloat16(xrow[i1.w]);
    *(bf16x8_t*)(xs + (size_t)n * K_DIM + c0) = u.v;
}

// ---------------------------------------------------------------------------
// Kernel 3: GEMM  C[n][o] = sum_k A[n][k]*B[o][k] + bias[o],
// scattered store: out[n][out_idx[o]] = C[n][o].
// 128x128 tile, BK=64, 4 waves (2x2), each wave 64x64 = 4x4 MFMA 16x16x32 bf16.
// global_load_lds (16B/lane) staging with XOR chunk swizzle:
//   physical 16B-slot p of LDS row r holds logical k-chunk p ^ (r&7)
// -> lane-contiguous LDS fill (required by global_load_lds) AND <=2-way bank
//    aliasing on the ds_read_b128 fragment reads (free, m136).
// ---------------------------------------------------------------------------
__global__ void __launch_bounds__(256, 2)
gemm_scatter_kernel(const __hip_bfloat16* __restrict__ A,   // [M][K]
                    const __hip_bfloat16* __restrict__ B,   // [N][K] (W_eff)
                    const float* __restrict__ bias,         // [N]
                    const int* __restrict__ oidx,           // [N]
                    float* __restrict__ out)                // [M][OUT_DIM]
{
    __shared__ __hip_bfloat16 As[128 * 64];
    __shared__ __hip_bfloat16 Bs[128 * 64];

    const int tid  = threadIdx.x;
    const int wave = tid >> 6;
    const int lane = tid & 63;
    const int m0 = blockIdx.y * 128;
    const int n0 = blockIdx.x * 128;

    const int wm = (wave >> 1) * 64;   // wave row offset in tile
    const int wn = (wave & 1) * 64;    // wave col offset in tile

    // staging: each inst covers 32 rows (8 lanes/row, 16B each), 4 insts/tile
    const int srow  = tid >> 3;        // 0..31
    const int sslot = tid & 7;         // physical 16B slot within row

    const int r15 = lane & 15;
    const int qd  = lane >> 4;

    f32x4_t acc[4][4] = {};

    for (int k0 = 0; k0 < K_DIM; k0 += 64) {
        #pragma unroll
        for (int it = 0; it < 4; ++it) {
            const int row = it * 32 + srow;
            const int q = sslot ^ (row & 7);                 // logical chunk to fetch
            const __hip_bfloat16* ga = A + (size_t)(m0 + row) * K_DIM + k0 + q * 8;
            const __hip_bfloat16* gb = B + (size_t)(n0 + row) * K_DIM + k0 + q * 8;
            // wave-uniform LDS base; HW scatters lane i at base + i*16
            load_lds16(ga, (void*)&As[(it * 32 + wave * 8) * 64]);
            load_lds16(gb, (void*)&Bs[(it * 32 + wave * 8) * 64]);
        }
        __syncthreads();

        #pragma unroll
        for (int s = 0; s < 2; ++s) {   // two k-steps of 32 within BK=64
            bf16x8_t af[4], bfr[4];
            #pragma unroll
            for (int i = 0; i < 4; ++i) {
                const int rowa = wm + i * 16 + r15;
                const int pa = (s * 4 + qd) ^ (rowa & 7);
                af[i] = *(const bf16x8_t*)&As[rowa * 64 + pa * 8];
                const int rowb = wn + i * 16 + r15;
                const int pb = (s * 4 + qd) ^ (rowb & 7);
                bfr[i] = *(const bf16x8_t*)&Bs[rowb * 64 + pb * 8];
            }
            #pragma unroll
            for (int i = 0; i < 4; ++i)
                #pragma unroll
                for (int j = 0; j < 4; ++j)
                    acc[i][j] = __builtin_amdgcn_mfma_f32_16x16x32_bf16(
                        af[i], bfr[j], acc[i][j], 0, 0, 0);
        }
        __syncthreads();
    }

    // Epilogue: bias + scatter columns through out_idx.
    // C/D layout (verified m89/m91): col = lane&15, row = (lane>>4)*4 + reg
    #pragma unroll
    for (int j = 0; j < 4; ++j) {
        const int gn = n0 + wn + j * 16 + r15;
        const int oc = oidx[gn];
        const float bv = bias[gn];
        #pragma unroll
        for (int i = 0; i < 4; ++i) {
            const int gm = m0 + wm + i * 16 + qd * 4;
            #pragma unroll
            for (int r = 0; r < 4; ++r)
                out[(size_t)(gm + r) * OUT_DIM + oc] = acc[i][j][r] + bv;
        }
    }
}

// ---------------------------------------------------------------------------
extern "C" void kernel_launch(void* const* d_in, const int* in_sizes, int n_in,
                              void* d_out, int out_size, void* d_ws, size_t ws_size,
                              hipStream_t stream) {
    const float* x      = (const float*)d_in[0];   // [2,4096,4096]
    const float* W_base = (const float*)d_in[1];   // [2048,2048]
    const float* b_base = (const float*)d_in[2];   // [2048]
    const float* lora_A = (const float*)d_in[3];   // [16,2048]
    const float* lora_B = (const float*)d_in[4];   // [2048,16]
    const int* in_idx   = (const int*)d_in[5];     // [2048]
    const int* out_idx  = (const int*)d_in[6];     // [2048]
    float* out = (float*)d_out;                    // [8192,4096]

    __hip_bfloat16* xs = (__hip_bfloat16*)d_ws;                         // 32 MB
    __hip_bfloat16* We = (__hip_bfloat16*)((char*)d_ws + (size_t)M_DIM * K_DIM * 2); // 8 MB

    // out is poisoned 0xAA each launch; non-selected columns must be zero.
    hipMemsetAsync(d_out, 0, (size_t)M_DIM * OUT_DIM * sizeof(float), stream);

    fold_w_kernel<<<dim3(K_DIM / 256, N_DIM), 256, 0, stream>>>(W_base, lora_A, lora_B, We);
    gather_cast_kernel<<<M_DIM, 256, 0, stream>>>(x, in_idx, xs);
    gemm_scatter_kernel<<<dim3(N_DIM / 128, M_DIM / 128), 256, 0, stream>>>(
        xs, We, b_base, out_idx, out);
}

// Round 2
// 345.151 us; speedup vs baseline: 1.0770x; 1.0770x over previous
//
#include <hip/hip_runtime.h>
#include <hip/hip_bf16.h>
#include <stdint.h>

// Problem constants
#define M_DIM 8192      // 2*4096 flattened batch
#define K_DIM 2048      // ACTIVE (in)
#define N_DIM 2048      // ACTIVE (out)
#define IN_DIM 4096     // ORIG_IN
#define OUT_DIM 4096    // ORIG_OUT
#define SCALING 2.0f    // 32/16

typedef __attribute__((ext_vector_type(8))) short bf16x8_t;  // 8 bf16 = 4 VGPRs
typedef __attribute__((ext_vector_type(4))) float f32x4_t;

__device__ __forceinline__ void load_lds16(const void* gptr, void* lptr) {
    __builtin_amdgcn_global_load_lds(
        (const __attribute__((address_space(1))) uint32_t*)(uintptr_t)gptr,
        (__attribute__((address_space(3))) uint32_t*)(uintptr_t)lptr,
        16, 0, 0);
}

// ---------------------------------------------------------------------------
// Kernel 1: fold LoRA into base weight, cast to bf16.
// ---------------------------------------------------------------------------
__global__ void fold_w_kernel(const float* __restrict__ Wb,
                              const float* __restrict__ lA,   // [16][2048]
                              const float* __restrict__ lB,   // [2048][16]
                              __hip_bfloat16* __restrict__ We) {
    const int k = blockIdx.x * 256 + threadIdx.x;
    const int o = blockIdx.y;
    float acc = Wb[(size_t)o * K_DIM + k];
    #pragma unroll
    for (int r = 0; r < 16; ++r)
        acc += SCALING * lB[o * 16 + r] * lA[r * K_DIM + k];
    We[(size_t)o * K_DIM + k] = __float2bfloat16(acc);
}

// ---------------------------------------------------------------------------
// Kernel 2: gather active input columns + cast to bf16, via LDS staging.
// Coalesced float4 global reads -> LDS -> scattered LDS reads (cheap) ->
// coalesced 16B bf16 writes.
// ---------------------------------------------------------------------------
__global__ void __launch_bounds__(256)
gather_cast_kernel(const float* __restrict__ x,
                   const int* __restrict__ idx,
                   __hip_bfloat16* __restrict__ xs) {
    __shared__ float row[IN_DIM];
    const int n = blockIdx.x;
    const float* xrow = x + (size_t)n * IN_DIM;
    #pragma unroll
    for (int i = 0; i < 4; ++i) {
        const int c = (i * 256 + threadIdx.x) * 4;
        *(float4*)&row[c] = *(const float4*)&xrow[c];
    }
    __syncthreads();
    const int c0 = threadIdx.x * 8;
    int4 i0 = *(const int4*)(idx + c0);
    int4 i1 = *(const int4*)(idx + c0 + 4);
    union { bf16x8_t v; __hip_bfloat16 h[8]; } u;
    u.h[0] = __float2bfloat16(row[i0.x]);
    u.h[1] = __float2bfloat16(row[i0.y]);
    u.h[2] = __float2bfloat16(row[i0.z]);
    u.h[3] = __float2bfloat16(row[i0.w]);
    u.h[4] = __float2bfloat16(row[i1.x]);
    u.h[5] = __float2bfloat16(row[i1.y]);
    u.h[6] = __float2bfloat16(row[i1.z]);
    u.h[7] = __float2bfloat16(row[i1.w]);
    *(bf16x8_t*)(xs + (size_t)n * K_DIM + c0) = u.v;
}

// ---------------------------------------------------------------------------
// Kernel 3: inverse index map. inv[oc] = n such that out_idx[n]==oc, else -1.
// out_idx is sorted -> binary search, no init needed, no races.
// ---------------------------------------------------------------------------
__global__ void build_inv_kernel(const int* __restrict__ oidx,
                                 int* __restrict__ inv) {
    const int c = blockIdx.x * 256 + threadIdx.x;   // 0..4095
    int lo = 0, hi = N_DIM;
    while (lo < hi) {
        const int mid = (lo + hi) >> 1;
        if (oidx[mid] < c) lo = mid + 1; else hi = mid;
    }
    inv[c] = (lo < N_DIM && oidx[lo] == c) ? lo : -1;
}

// ---------------------------------------------------------------------------
// Kernel 4: GEMM  C = A @ B^T + bias.  128x128 tile, BK=64, 4 waves (2x2),
// each wave 64x64 = 4x4 MFMA 16x16x32 bf16.  global_load_lds 16B staging with
// XOR chunk swizzle (lane-contiguous fill + <=2-way bank aliasing on reads).
// COMPACT=true: write bf16 C[M][N] coalesced (bias added).
// COMPACT=false (ws fallback): scatter fp32 into out via oidx.
// ---------------------------------------------------------------------------
template <bool COMPACT>
__global__ void __launch_bounds__(256, 2)
gemm_kernel(const __hip_bfloat16* __restrict__ A,   // [M][K]
            const __hip_bfloat16* __restrict__ B,   // [N][K] (W_eff)
            const float* __restrict__ bias,         // [N]
            const int* __restrict__ oidx,           // [N]
            float* __restrict__ out,                // [M][OUT_DIM] (fallback)
            __hip_bfloat16* __restrict__ Cc)        // [M][N] (compact)
{
    __shared__ __hip_bfloat16 As[128 * 64];
    __shared__ __hip_bfloat16 Bs[128 * 64];

    const int tid  = threadIdx.x;
    const int wave = tid >> 6;
    const int lane = tid & 63;
    const int m0 = blockIdx.y * 128;
    const int n0 = blockIdx.x * 128;

    const int wm = (wave >> 1) * 64;
    const int wn = (wave & 1) * 64;

    const int srow  = tid >> 3;        // 0..31
    const int sslot = tid & 7;         // physical 16B slot within row

    const int r15 = lane & 15;
    const int qd  = lane >> 4;

    f32x4_t acc[4][4] = {};

    for (int k0 = 0; k0 < K_DIM; k0 += 64) {
        #pragma unroll
        for (int it = 0; it < 4; ++it) {
            const int row = it * 32 + srow;
            const int q = sslot ^ (row & 7);
            const __hip_bfloat16* ga = A + (size_t)(m0 + row) * K_DIM + k0 + q * 8;
            const __hip_bfloat16* gb = B + (size_t)(n0 + row) * K_DIM + k0 + q * 8;
            load_lds16(ga, (void*)&As[(it * 32 + wave * 8) * 64]);
            load_lds16(gb, (void*)&Bs[(it * 32 + wave * 8) * 64]);
        }
        __syncthreads();

        #pragma unroll
        for (int s = 0; s < 2; ++s) {
            bf16x8_t af[4], bfr[4];
            #pragma unroll
            for (int i = 0; i < 4; ++i) {
                const int rowa = wm + i * 16 + r15;
                const int pa = (s * 4 + qd) ^ (rowa & 7);
                af[i] = *(const bf16x8_t*)&As[rowa * 64 + pa * 8];
                const int rowb = wn + i * 16 + r15;
                const int pb = (s * 4 + qd) ^ (rowb & 7);
                bfr[i] = *(const bf16x8_t*)&Bs[rowb * 64 + pb * 8];
            }
            #pragma unroll
            for (int i = 0; i < 4; ++i)
                #pragma unroll
                for (int j = 0; j < 4; ++j)
                    acc[i][j] = __builtin_amdgcn_mfma_f32_16x16x32_bf16(
                        af[i], bfr[j], acc[i][j], 0, 0, 0);
        }
        __syncthreads();
    }

    // C/D layout (verified m89/m91): col = lane&15, row = (lane>>4)*4 + reg
    #pragma unroll
    for (int j = 0; j < 4; ++j) {
        const int gn = n0 + wn + j * 16 + r15;
        const float bv = bias[gn];
        if (COMPACT) {
            #pragma unroll
            for (int i = 0; i < 4; ++i) {
                const int gm = m0 + wm + i * 16 + qd * 4;
                #pragma unroll
                for (int r = 0; r < 4; ++r)
                    Cc[(size_t)(gm + r) * N_DIM + gn] =
                        __float2bfloat16(acc[i][j][r] + bv);
            }
        } else {
            const int oc = oidx[gn];
            #pragma unroll
            for (int i = 0; i < 4; ++i) {
                const int gm = m0 + wm + i * 16 + qd * 4;
                #pragma unroll
                for (int r = 0; r < 4; ++r)
                    out[(size_t)(gm + r) * OUT_DIM + oc] = acc[i][j][r] + bv;
            }
        }
    }
}

// ---------------------------------------------------------------------------
// Kernel 5: expand compact C into full output (zeros for unselected cols).
// Fully coalesced float4 writes -> replaces the 128 MB memset too.
// ---------------------------------------------------------------------------
__global__ void __launch_bounds__(256)
scatter_out_kernel(const __hip_bfloat16* __restrict__ C,   // [M][N]
                   const int* __restrict__ inv,            // [OUT_DIM]
                   float* __restrict__ out) {              // [M][OUT_DIM]
    const int row = blockIdx.y;
    const int c0 = (blockIdx.x * 256 + threadIdx.x) * 4;
    const __hip_bfloat16* crow = C + (size_t)row * N_DIM;
    const int4 iv = *(const int4*)(inv + c0);
    float4 v;
    v.x = (iv.x >= 0) ? __bfloat162float(crow[iv.x]) : 0.0f;
    v.y = (iv.y >= 0) ? __bfloat162float(crow[iv.y]) : 0.0f;
    v.z = (iv.z >= 0) ? __bfloat162float(crow[iv.z]) : 0.0f;
    v.w = (iv.w >= 0) ? __bfloat162float(crow[iv.w]) : 0.0f;
    *(float4*)(out + (size_t)row * OUT_DIM + c0) = v;
}

// ---------------------------------------------------------------------------
extern "C" void kernel_launch(void* const* d_in, const int* in_sizes, int n_in,
                              void* d_out, int out_size, void* d_ws, size_t ws_size,
                              hipStream_t stream) {
    const float* x      = (const float*)d_in[0];   // [2,4096,4096]
    const float* W_base = (const float*)d_in[1];   // [2048,2048]
    const float* b_base = (const float*)d_in[2];   // [2048]
    const float* lora_A = (const float*)d_in[3];   // [16,2048]
    const float* lora_B = (const float*)d_in[4];   // [2048,16]
    const int* in_idx   = (const int*)d_in[5];     // [2048]
    const int* out_idx  = (const int*)d_in[6];     // [2048]
    float* out = (float*)d_out;                    // [8192,4096]

    const size_t sz_xs = (size_t)M_DIM * K_DIM * 2;   // 32 MB
    const size_t sz_We = (size_t)N_DIM * K_DIM * 2;   //  8 MB
    const size_t sz_C  = (size_t)M_DIM * N_DIM * 2;   // 32 MB
    const size_t sz_inv = (size_t)OUT_DIM * 4;        // 16 KB

    __hip_bfloat16* xs = (__hip_bfloat16*)d_ws;
    __hip_bfloat16* We = (__hip_bfloat16*)((char*)d_ws + sz_xs);
    __hip_bfloat16* Cc = (__hip_bfloat16*)((char*)d_ws + sz_xs + sz_We);
    int* inv           = (int*)((char*)d_ws + sz_xs + sz_We + sz_C);

    fold_w_kernel<<<dim3(K_DIM / 256, N_DIM), 256, 0, stream>>>(W_base, lora_A, lora_B, We);
    gather_cast_kernel<<<M_DIM, 256, 0, stream>>>(x, in_idx, xs);

    if (ws_size >= sz_xs + sz_We + sz_C + sz_inv) {
        // Compact path: GEMM -> bf16 C, then coalesced expand (no memset).
        build_inv_kernel<<<OUT_DIM / 256, 256, 0, stream>>>(out_idx, inv);
        gemm_kernel<true><<<dim3(N_DIM / 128, M_DIM / 128), 256, 0, stream>>>(
            xs, We, b_base, out_idx, out, Cc);
        scatter_out_kernel<<<dim3(OUT_DIM / (256 * 4), M_DIM), 256, 0, stream>>>(
            Cc, inv, out);
    } else {
        // Fallback (round-1 behavior): memset + scattered epilogue.
        hipMemsetAsync(d_out, 0, (size_t)M_DIM * OUT_DIM * sizeof(float), stream);
        gemm_kernel<false><<<dim3(N_DIM / 128, M_DIM / 128), 256, 0, stream>>>(
            xs, We, b_base, out_idx, out, Cc);
    }
}